// Round 4
// baseline (2697.402 us; speedup 1.0000x reference)
//
#include <hip/hip_runtime.h>

typedef _Float16 f16;
typedef __attribute__((ext_vector_type(8))) _Float16 f16x8;
typedef __attribute__((ext_vector_type(4))) float f32x4;

#define E_TOTAL 160000
#define NN 20000
#define NGRAPH 64

__device__ __forceinline__ void gl_lds16(const void* g, void* l) {
    __builtin_amdgcn_global_load_lds((const __attribute__((address_space(1))) void*)g,
                                     (__attribute__((address_space(3))) void*)l, 16, 0, 0);
}

// ---------------- fp16 MFMA GEMM, 256x256 tile, BK=64, 8 waves, counted-vmcnt pipeline -------
// C[M,N] = act(A[M,lda] @ Bt[N,K]^T + bias [+aux]).  K mult of 64, N mult of 256.
// A rows up to gridDim.y*256 must be readable; Bt has N rows (zero-padded cols to K).
// AUXU: += utab[uidx[row]*N + col]   AUXX: += dot(x9[xi*9..], W9[q*N + col])
template <int RELU, int AUXU, int AUXX>
__global__ __launch_bounds__(512, 2) void hgemm2(
    int M, int N, int K,
    const f16* __restrict__ A, int lda,
    const f16* __restrict__ Bt,
    f16* __restrict__ C, int ldc,
    const float* __restrict__ bias,
    const f16* __restrict__ utab, const int* __restrict__ uidx,
    const float* __restrict__ x9, const int* __restrict__ xidx, const float* __restrict__ W9)
{
    __shared__ __align__(16) char Ash[2][32768];
    __shared__ __align__(16) char Bsh[2][32768];
    __shared__ float Ws9[AUXX ? 2304 : 1];   // 9 x 256

    const int tid  = threadIdx.x;
    const int lane = tid & 63;
    const int w    = tid >> 6;            // 0..7
    const int bm = blockIdx.y * 256;
    const int bn = blockIdx.x * 256;
    const int wm = (w >> 2) * 128;        // 2 waves along M
    const int wn = (w & 3) * 64;          // 4 waves along N
    const int fr = lane & 15;
    const int kq = lane >> 4;

    const char* Ab = (const char*)A;
    const char* Bb = (const char*)Bt;
    const size_t lda2 = (size_t)lda * 2;
    const size_t ldb2 = (size_t)K * 2;

    f32x4 acc[8][4] = {};

    // staging addresses: 32 KB per operand per K-step = 8 waves x 4 insts x 1 KB
    size_t offA[4], offB[4];
    int ldsoff[4];
#pragma unroll
    for (int i = 0; i < 4; ++i) {
        int cch = w * 4 + i;
        int L = cch * 1024 + lane * 16;
        int row = L >> 7;
        int scb = (L & 127) ^ ((row & 7) << 4);  // pre-swizzled global source
        offA[i] = (size_t)(bm + row) * lda2 + scb;
        offB[i] = (size_t)(bn + row) * ldb2 + scb;
        ldsoff[i] = cch * 1024;                  // wave-uniform LDS base
    }

    const int NT = K >> 6;

    // prologue: stage tile 0 into buf 0
#pragma unroll
    for (int i = 0; i < 4; ++i) gl_lds16(Ab + offA[i], Ash[0] + ldsoff[i]);
#pragma unroll
    for (int i = 0; i < 4; ++i) gl_lds16(Bb + offB[i], Bsh[0] + ldsoff[i]);

    int cur = 0;
    for (int t = 0; t < NT; ++t) {
        if (t + 1 < NT) {
            size_t kb = (size_t)(t + 1) << 7;   // k0*2 bytes
#pragma unroll
            for (int i = 0; i < 4; ++i) gl_lds16(Ab + offA[i] + kb, Ash[cur ^ 1] + ldsoff[i]);
#pragma unroll
            for (int i = 0; i < 4; ++i) gl_lds16(Bb + offB[i] + kb, Bsh[cur ^ 1] + ldsoff[i]);
            asm volatile("s_waitcnt vmcnt(8)" ::: "memory");   // tile t landed; t+1 in flight
        } else {
            asm volatile("s_waitcnt vmcnt(0)" ::: "memory");
        }
        __builtin_amdgcn_s_barrier();
        __builtin_amdgcn_sched_barrier(0);

        const char* As = Ash[cur];
        const char* Bs = Bsh[cur];

        f16x8 bv[2][4];
#pragma unroll
        for (int ks = 0; ks < 2; ++ks) {
            const int cb = (ks * 32 + kq * 8) * 2;
#pragma unroll
            for (int ni = 0; ni < 4; ++ni) {
                int r = wn + ni * 16 + fr;
                bv[ks][ni] = *(const f16x8*)(Bs + r * 128 + (cb ^ ((r & 7) << 4)));
            }
        }
        __builtin_amdgcn_s_setprio(1);
#pragma unroll
        for (int mi = 0; mi < 8; ++mi) {
            int r = wm + mi * 16 + fr;
            int sw = (r & 7) << 4;
            f16x8 a0 = *(const f16x8*)(As + r * 128 + ((kq * 16) ^ sw));
            f16x8 a1 = *(const f16x8*)(As + r * 128 + ((64 + kq * 16) ^ sw));
#pragma unroll
            for (int ni = 0; ni < 4; ++ni)
                acc[mi][ni] = __builtin_amdgcn_mfma_f32_16x16x32_f16(a0, bv[0][ni], acc[mi][ni], 0, 0, 0);
#pragma unroll
            for (int ni = 0; ni < 4; ++ni)
                acc[mi][ni] = __builtin_amdgcn_mfma_f32_16x16x32_f16(a1, bv[1][ni], acc[mi][ni], 0, 0, 0);
        }
        __builtin_amdgcn_s_setprio(0);
        cur ^= 1;
    }

    if (AUXX) {
        for (int t = tid; t < 9 * 256; t += 512)
            Ws9[t] = W9[(size_t)(t >> 8) * N + bn + (t & 255)];
        __syncthreads();
    }

    // C/D layout: col = lane&15, row = kq*4 + reg
#pragma unroll
    for (int mi = 0; mi < 8; ++mi) {
        int r0 = bm + wm + mi * 16 + kq * 4;
#pragma unroll
        for (int r = 0; r < 4; ++r) {
            int grow = r0 + r;
            if (grow >= M) continue;
            int ub = 0;
            if (AUXU) ub = uidx[grow];
            float xv[9];
            if (AUXX) {
                int xi = xidx ? xidx[grow] : grow;
#pragma unroll
                for (int q = 0; q < 9; ++q) xv[q] = x9[(size_t)xi * 9 + q];
            }
#pragma unroll
            for (int ni = 0; ni < 4; ++ni) {
                int lcol = wn + ni * 16 + fr;
                int col = bn + lcol;
                float v = acc[mi][ni][r] + bias[col];
                if (AUXU) v += (float)utab[(size_t)ub * N + col];
                if (AUXX) {
                    float s = 0.f;
#pragma unroll
                    for (int q = 0; q < 9; ++q) s = fmaf(xv[q], Ws9[q * 256 + lcol], s);
                    v += s;
                }
                if (RELU) v = fmaxf(v, 0.f);
                C[(size_t)grow * ldc + col] = (f16)v;
            }
        }
    }
}

// ---- weight slice transpose: Wt[n][k] = W[(r0+k)*N + n], k<Ksub, pad to Kp with 0 ----
__global__ void k_wt(const float* __restrict__ W, f16* __restrict__ Wt,
                     int r0, int Ksub, int N, int Kp)
{
    size_t t = (size_t)blockIdx.x * 256 + threadIdx.x;
    if (t >= (size_t)N * Kp) return;
    int n = (int)(t / Kp), k = (int)(t % Kp);
    Wt[t] = (k < Ksub) ? (f16)W[(size_t)(r0 + k) * N + n] : (f16)0.f;
}

// ---- u2h = f16(u @ Wsel + bsel)  split-K ----
__global__ __launch_bounds__(256) void k_u2(const float* __restrict__ u,
                                            const float* __restrict__ Wsel,
                                            const float* __restrict__ bsel,
                                            f16* __restrict__ u2h)
{
    __shared__ float us[4096];
    __shared__ float red[4][64];
    const int g = blockIdx.y;
    const int c0 = blockIdx.x * 64;
    const int col = threadIdx.x & 63;
    const int kp = threadIdx.x >> 6;
    for (int i = threadIdx.x; i < 4096; i += 256) us[i] = u[(size_t)g * 4096 + i];
    __syncthreads();
    float acc = 0.f;
    for (int k = kp * 1024; k < kp * 1024 + 1024; ++k)
        acc = fmaf(us[k], Wsel[(size_t)k * 256 + c0 + col], acc);
    red[kp][col] = acc;
    __syncthreads();
    if (kp == 0) {
        float v = red[0][col] + red[1][col] + red[2][col] + red[3][col] + bsel[c0 + col];
        u2h[(size_t)g * 256 + c0 + col] = (f16)v;
    }
}

// ---- per-edge gather: feat64 = [x[row](9), x[col](9), ea(1), 0-pad], ebat = batch[row] ----
__global__ void k_gather19(int e0, int Ce,
                           const float* __restrict__ x, const float* __restrict__ eattr,
                           const int* __restrict__ ei, const int* __restrict__ batch,
                           f16* __restrict__ feat, int* __restrict__ ebat)
{
    size_t t = (size_t)blockIdx.x * 256 + threadIdx.x;
    if (t >= (size_t)Ce * 64) return;
    int i = (int)(t >> 6), j = (int)(t & 63);
    int e = e0 + i;
    float v = 0.f;
    if (j < 9)        v = x[ei[e] * 9 + j];
    else if (j < 18)  v = x[ei[E_TOTAL + e] * 9 + (j - 9)];
    else if (j == 18) v = eattr[e];
    else if (j == 19) ebat[i] = batch[ei[e]];
    feat[t] = (f16)v;
}

__global__ void k_scatter(int e0, int Ce, const f16* __restrict__ h2,
                          const int* __restrict__ ei, float* __restrict__ ssum)
{
    size_t t = (size_t)blockIdx.x * 256 + threadIdx.x;
    if (t >= (size_t)Ce * 512) return;
    int i = (int)(t >> 9), j = (int)(t & 511);
    atomicAdd(ssum + (size_t)ei[e0 + i] * 512 + j, (float)h2[t]);
}

__global__ void k_cnt(const int* __restrict__ ei, float* __restrict__ cnt)
{
    int t = blockIdx.x * 256 + threadIdx.x;
    if (t < E_TOTAL) atomicAdd(cnt + ei[t], 1.0f);
}

__global__ void k_agg(const float* __restrict__ ssum, const float* __restrict__ cnt,
                      f16* __restrict__ agg)
{
    size_t t = (size_t)blockIdx.x * 256 + threadIdx.x;
    if (t >= (size_t)NN * 512) return;
    int n = (int)(t >> 9);
    agg[t] = (f16)(ssum[t] / fmaxf(cnt[n], 1.f));
}

__global__ void k_final(const f16* __restrict__ z1, const float* __restrict__ W,
                        const float* __restrict__ b, float* __restrict__ out)
{
    int gt = blockIdx.x * 256 + threadIdx.x;
    int row = gt >> 6;
    int lane = threadIdx.x & 63;
    if (row >= NN) return;
    float s = 0.f;
#pragma unroll
    for (int c = lane; c < 512; c += 64) s += (float)z1[(size_t)row * 512 + c] * W[c];
#pragma unroll
    for (int off = 32; off; off >>= 1) s += __shfl_down(s, off);
    if (lane == 0) out[row] = s + b[0];
}

// ---------------- launch ----------------

extern "C" void kernel_launch(void* const* d_in, const int* in_sizes, int n_in,
                              void* d_out, int out_size, void* d_ws, size_t ws_size,
                              hipStream_t stream)
{
    const float* x     = (const float*)d_in[0];
    const float* eattr = (const float*)d_in[1];
    const float* u     = (const float*)d_in[2];
    const int*   ei    = (const int*)d_in[3];
    const int*   batch = (const int*)d_in[4];
    const float* Wsel  = (const float*)d_in[5];
    const float* bsel  = (const float*)d_in[6];
    const float* eW1 = (const float*)d_in[7],  * eb1 = (const float*)d_in[8];
    const float* eW2 = (const float*)d_in[9],  * eb2 = (const float*)d_in[10];
    const float* eW3 = (const float*)d_in[11], * eb3 = (const float*)d_in[12];
    const float* eW4 = (const float*)d_in[13], * eb4 = (const float*)d_in[14];
    const float* eW5 = (const float*)d_in[15], * eb5 = (const float*)d_in[16];
    const float* n1W1 = (const float*)d_in[17], * n1b1 = (const float*)d_in[18];
    const float* n1W2 = (const float*)d_in[19], * n1b2 = (const float*)d_in[20];
    const float* n2W1 = (const float*)d_in[21], * n2b1 = (const float*)d_in[22];
    const float* n2W2 = (const float*)d_in[23], * n2b2 = (const float*)d_in[24];
    float* out = (float*)d_out;

    char* ws = (char*)d_ws;
    size_t off = 0;
    auto alc = [&](size_t bytes) { char* p = ws + off; off += (bytes + 255) & ~(size_t)255; return p; };

    float* ssum  = (float*)alc((size_t)NN * 512 * 4);
    float* cnt   = (float*)alc((size_t)NN * 4);
    float* zbias = (float*)alc(1024 * 4);
    f16* u2h     = (f16*)alc((size_t)256 * 256 * 2);      // 64 valid rows, padded to 256
    f16* ubias_e = (f16*)alc((size_t)64 * 1024 * 2);
    f16* ubias_n = (f16*)alc((size_t)64 * 512 * 2);
    f16* eW1t19  = (f16*)alc((size_t)1024 * 64 * 2);
    f16* eW1ut   = (f16*)alc((size_t)1024 * 256 * 2);
    f16* eW2t    = (f16*)alc((size_t)1024 * 1024 * 2);
    f16* eW3t    = (f16*)alc((size_t)1024 * 1024 * 2);
    f16* eW4t    = (f16*)alc((size_t)1024 * 1024 * 2);
    f16* eW5t    = (f16*)alc((size_t)512 * 1024 * 2);
    f16* n1W1et  = (f16*)alc((size_t)512 * 512 * 2);
    f16* n1W2t   = (f16*)alc((size_t)512 * 512 * 2);
    f16* n2W1et  = (f16*)alc((size_t)512 * 512 * 2);
    f16* n2W1ut  = (f16*)alc((size_t)512 * 256 * 2);
    f16* agg     = (f16*)alc((size_t)20224 * 512 * 2);
    f16* z1      = (f16*)alc((size_t)20224 * 512 * 2);
    size_t fixed = off;

    // chunk region: per-edge = feat64 (128B) + buf1 (2048B) + buf2 (2048B) + ebat (4B)
    size_t per_edge = 64 * 2 + 1024 * 2 + 1024 * 2 + 4;
    size_t avail = ws_size > fixed ? ws_size - fixed : 0;
    long long Cll = (long long)(avail / per_edge);
    int C = (int)((Cll / 256) * 256);
    if (C > E_TOTAL) C = E_TOTAL;   // 160000 = 625*256
    if (C < 256) C = 256;

    f16* featc = (f16*)(ws + fixed);
    f16* buf1  = featc + (size_t)C * 64;
    f16* buf2  = buf1 + (size_t)C * 1024;
    int* ebat  = (int*)(buf2 + (size_t)C * 1024);

    size_t zlen = (size_t)((char*)zbias - (char*)ssum) + 1024 * 4;
    hipMemsetAsync(ssum, 0, zlen, stream);

    auto wt = [&](const float* W, f16* Wt, int r0, int Ksub, int N, int Kp) {
        size_t tot = (size_t)N * Kp;
        k_wt<<<(unsigned)((tot + 255) / 256), 256, 0, stream>>>(W, Wt, r0, Ksub, N, Kp);
    };
    wt(eW1, eW1t19, 0, 19, 1024, 64);
    wt(eW1, eW1ut, 19, 256, 1024, 256);
    wt(eW2, eW2t, 0, 1024, 1024, 1024);
    wt(eW3, eW3t, 0, 1024, 1024, 1024);
    wt(eW4, eW4t, 0, 1024, 1024, 1024);
    wt(eW5, eW5t, 0, 1024, 512, 1024);
    wt(n1W1, n1W1et, 9, 512, 512, 512);
    wt(n1W2, n1W2t, 0, 512, 512, 512);
    wt(n2W1, n2W1et, 9, 512, 512, 512);
    wt(n2W1, n2W1ut, 521, 256, 512, 256);

    k_u2<<<dim3(4, NGRAPH), 256, 0, stream>>>(u, Wsel, bsel, u2h);
    k_cnt<<<(E_TOTAL + 255) / 256, 256, 0, stream>>>(ei, cnt);

    // u-contribution tables (include the layer bias)
    hgemm2<0,0,0><<<dim3(4, 1), 512, 0, stream>>>(64, 1024, 256, u2h, 256, eW1ut,
        ubias_e, 1024, eb1, nullptr, nullptr, nullptr, nullptr, nullptr);
    hgemm2<0,0,0><<<dim3(2, 1), 512, 0, stream>>>(64, 512, 256, u2h, 256, n2W1ut,
        ubias_n, 512, n2b1, nullptr, nullptr, nullptr, nullptr, nullptr);

    for (int e0 = 0; e0 < E_TOTAL; e0 += C) {
        int Ce = E_TOTAL - e0 < C ? E_TOTAL - e0 : C;
        int gy = (Ce + 255) / 256;

        k_gather19<<<(unsigned)(((size_t)Ce * 64 + 255) / 256), 256, 0, stream>>>(
            e0, Ce, x, eattr, ei, batch, featc, ebat);

        hgemm2<1,1,0><<<dim3(4, gy), 512, 0, stream>>>(Ce, 1024, 64, featc, 64, eW1t19,
            buf1, 1024, zbias, ubias_e, ebat, nullptr, nullptr, nullptr);
        hgemm2<1,0,0><<<dim3(4, gy), 512, 0, stream>>>(Ce, 1024, 1024, buf1, 1024, eW2t,
            buf2, 1024, eb2, nullptr, nullptr, nullptr, nullptr, nullptr);
        hgemm2<1,0,0><<<dim3(4, gy), 512, 0, stream>>>(Ce, 1024, 1024, buf2, 1024, eW3t,
            buf1, 1024, eb3, nullptr, nullptr, nullptr, nullptr, nullptr);
        hgemm2<1,0,0><<<dim3(4, gy), 512, 0, stream>>>(Ce, 1024, 1024, buf1, 1024, eW4t,
            buf2, 1024, eb4, nullptr, nullptr, nullptr, nullptr, nullptr);
        hgemm2<0,0,0><<<dim3(2, gy), 512, 0, stream>>>(Ce, 512, 1024, buf2, 1024, eW5t,
            buf1, 512, eb5, nullptr, nullptr, nullptr, nullptr, nullptr);   // e -> buf1

        hgemm2<1,0,1><<<dim3(2, gy), 512, 0, stream>>>(Ce, 512, 512, buf1, 512, n1W1et,
            buf2, 512, n1b1, nullptr, nullptr, x, ei + E_TOTAL + e0, n1W1);  // h1 -> buf2
        hgemm2<1,0,0><<<dim3(2, gy), 512, 0, stream>>>(Ce, 512, 512, buf2, 512, n1W2t,
            buf1, 512, n1b2, nullptr, nullptr, nullptr, nullptr, nullptr);   // h2 -> buf1

        k_scatter<<<(unsigned)(((size_t)Ce * 512 + 255) / 256), 256, 0, stream>>>(
            e0, Ce, buf1, ei, ssum);
    }

    // readout
    k_agg<<<(unsigned)(((size_t)NN * 512 + 255) / 256), 256, 0, stream>>>(ssum, cnt, agg);
    hgemm2<1,1,1><<<dim3(2, 79), 512, 0, stream>>>(NN, 512, 512, agg, 512, n2W1et,
        z1, 512, zbias, ubias_n, batch, x, nullptr, n2W1);
    k_final<<<(NN * 64 + 255) / 256, 256, 0, stream>>>(z1, n2W2, n2b2, out);
}